// Round 6
// baseline (1732.036 us; speedup 1.0000x reference)
//
#include <hip/hip_runtime.h>
#include <hip/hip_bf16.h>
#include <hip/hip_fp16.h>
#include <stdint.h>

#define H 4
#define HID 64
#define CDIM 256   /* = H*HID = IN = FC */
#define OUTC 4
#define ALPHA 0.2f
#define NW 16      /* number of float weight inputs (d_in[2..17]) */

typedef __attribute__((ext_vector_type(8))) _Float16 f16x8;
typedef __attribute__((ext_vector_type(4))) float f32x4;

// ---------------------------------------------------------------------------
// dtype detection (R2/R4/R5-proven; real answer on this harness: fp32, flag=0)
// ---------------------------------------------------------------------------
__global__ void detect_k(const uint32_t* __restrict__ xw, int* __restrict__ flag) {
    __shared__ int sd[256];
    int t = threadIdx.x;
    int hits = 0;
    for (int i = 0; i < 16; ++i) {
        uint32_t w = xw[t * 16 + i];
        uint32_t ex = (w >> 7) & 0xffu;
        if (ex >= 100u && ex <= 145u) hits++;
    }
    sd[t] = hits;
    __syncthreads();
    for (int s = 128; s > 0; s >>= 1) {
        if (t < s) sd[t] += sd[t + s];
        __syncthreads();
    }
    if (t == 0) *flag = (sd[0] > 3000) ? 1 : 0;
}

// ---------------------------------------------------------------------------
// Convert all 16 weight tensors to fp32 AND fp16 in ws (branch on flag).
// ---------------------------------------------------------------------------
struct WPtrs {
    const void* p[NW];
    int sz[NW];
    int off[NW];
};

__global__ void convert_k(WPtrs ptrs, float* __restrict__ outf, __half* __restrict__ outh,
                          const int* __restrict__ flag) {
    int which = blockIdx.y;
    int n = ptrs.sz[which];
    int i = blockIdx.x * 256 + threadIdx.x;
    if (i >= n) return;
    float v;
    if (*flag) v = __bfloat162float(((const __hip_bfloat16*)ptrs.p[which])[i]);
    else       v = ((const float*)ptrs.p[which])[i];
    outf[ptrs.off[which] + i] = v;
    outh[ptrs.off[which] + i] = __float2half(v);
}

// ---------------------------------------------------------------------------
// CSR build: histogram -> scan -> scatter
// ---------------------------------------------------------------------------
__global__ void hist_k(const int* __restrict__ srcI, int* __restrict__ counts, int Ee) {
    int e = blockIdx.x * 256 + threadIdx.x;
    if (e < Ee) atomicAdd(&counts[srcI[e]], 1);
}

__global__ void scan1_k(const int* __restrict__ counts, int* __restrict__ bs, int Nn) {
    __shared__ int sd[256];
    int t = threadIdx.x;
    int i = blockIdx.x * 256 + t;
    sd[t] = (i < Nn) ? counts[i] : 0;
    __syncthreads();
    for (int s = 128; s > 0; s >>= 1) {
        if (t < s) sd[t] += sd[t + s];
        __syncthreads();
    }
    if (t == 0) bs[blockIdx.x] = sd[0];
}

__global__ void scan2_k(int* __restrict__ bs, int nb) {
    __shared__ int sd[512];
    int t = threadIdx.x;
    int v = (t < nb) ? bs[t] : 0;
    sd[t] = v;
    __syncthreads();
    for (int offm = 1; offm < 512; offm <<= 1) {
        int add = (t >= offm) ? sd[t - offm] : 0;
        __syncthreads();
        sd[t] += add;
        __syncthreads();
    }
    if (t < nb) bs[t] = sd[t] - v;   // exclusive
}

__global__ void scan3_k(const int* __restrict__ counts, const int* __restrict__ bs,
                        int* __restrict__ rowStart, int* __restrict__ cur, int Nn, int Ee) {
    __shared__ int sd[256];
    int t = threadIdx.x;
    int i = blockIdx.x * 256 + t;
    int v = (i < Nn) ? counts[i] : 0;
    sd[t] = v;
    __syncthreads();
    for (int offm = 1; offm < 256; offm <<= 1) {
        int add = (t >= offm) ? sd[t - offm] : 0;
        __syncthreads();
        sd[t] += add;
        __syncthreads();
    }
    int excl = sd[t] - v + bs[blockIdx.x];
    if (i < Nn) { rowStart[i] = excl; cur[i] = excl; }
    if (i == Nn) rowStart[i] = Ee;
}

__global__ void scatter_k(const int* __restrict__ srcI, const int* __restrict__ dstI,
                          int* __restrict__ cur, int* __restrict__ colI, int Ee) {
    int e = blockIdx.x * 256 + threadIdx.x;
    if (e < Ee) {
        int p = atomicAdd(&cur[srcI[e]], 1);
        colI[p] = dstI[e];
    }
}

// ---------------------------------------------------------------------------
// f16 MFMA GEMM, 128x128 tile / 4 waves, BK=32, mfma_f32_16x16x32_f16.
// AMODE 0: A = raw x (fp32 or bf16 per *flag), convert to fp16 in staging.
// AMODE 1: A = fp16 n-major [M][256].
// OMODE 0: fp32 n-major out + bias + relu (collator).
// OMODE 1: fp16 HEAD-MAJOR table out hT[head][M][64] (pre-relu, no bias) and
//          fused attention scores: a1v/a2v[n][head] = h[n,head,:]·a{1,2}w + b.
//          (head = 64 dims sits entirely in one 128-col block -> no atomics.)
// ---------------------------------------------------------------------------
template <int AMODE, int OMODE>
__global__ __launch_bounds__(256) void gemm_k(
    const void* __restrict__ Ap, const __half* __restrict__ B,
    const float* __restrict__ bias, void* __restrict__ Cp, int M,
    const int* __restrict__ flagp,
    const float* __restrict__ a1w, const float* __restrict__ a1b,
    const float* __restrict__ a2w, const float* __restrict__ a2b,
    float* __restrict__ a1v, float* __restrict__ a2v)
{
    __shared__ __align__(16) char smem[128 * 136 * 2];   // 34.8 KB
    short* As = (short*)smem;              // 128*40 shorts
    short* Bs = (short*)(smem + 10240);
    const int tid  = threadIdx.x;
    const int row0 = blockIdx.x * 128;
    const int col0 = blockIdx.y * 128;
    const int wave = tid >> 6, lane = tid & 63;
    const int m0w = (wave & 1) * 64;
    const int n0w = (wave >> 1) * 64;
    const int lm = lane & 15, lg = lane >> 4;
    const int isbf = (AMODE == 0) ? *flagp : 0;

    f32x4 acc[4][4] = {};

    for (int k0 = 0; k0 < CDIM; k0 += 32) {
        #pragma unroll
        for (int l = 0; l < 2; ++l) {
            int c = tid + l * 256;
            int m = c >> 2, kc = c & 3;
            int gr = row0 + m;
            uint4 q = make_uint4(0u, 0u, 0u, 0u);
            if constexpr (AMODE == 1) {
                const __half* A = (const __half*)Ap;
                if (gr < M) q = *(const uint4*)(A + (size_t)gr * CDIM + k0 + kc * 8);
            } else {
                if (gr < M) {
                    __half hv[8];
                    if (isbf) {
                        const uint4 qb = *(const uint4*)((const __hip_bfloat16*)Ap
                                           + (size_t)gr * CDIM + k0 + kc * 8);
                        const uint32_t* w = (const uint32_t*)&qb;
                        #pragma unroll
                        for (int p = 0; p < 4; ++p) {
                            hv[2*p]   = __float2half(__uint_as_float((w[p] & 0xffffu) << 16));
                            hv[2*p+1] = __float2half(__uint_as_float(w[p] & 0xffff0000u));
                        }
                    } else {
                        const float* A = (const float*)Ap + (size_t)gr * CDIM + k0 + kc * 8;
                        const float4 f0 = *(const float4*)A;
                        const float4 f1 = *(const float4*)(A + 4);
                        hv[0]=__float2half(f0.x); hv[1]=__float2half(f0.y);
                        hv[2]=__float2half(f0.z); hv[3]=__float2half(f0.w);
                        hv[4]=__float2half(f1.x); hv[5]=__float2half(f1.y);
                        hv[6]=__float2half(f1.z); hv[7]=__float2half(f1.w);
                    }
                    q = *(uint4*)hv;
                }
            }
            *(uint4*)(&As[m * 40 + kc * 8]) = q;
        }
        #pragma unroll
        for (int l = 0; l < 2; ++l) {
            int c = tid + l * 256;
            int nn = c >> 2, kc = c & 3;
            uint4 q = *(const uint4*)(B + (size_t)(col0 + nn) * CDIM + k0 + kc * 8);
            *(uint4*)(&Bs[nn * 40 + kc * 8]) = q;
        }
        __syncthreads();
        f16x8 af[4], bfr[4];
        #pragma unroll
        for (int i = 0; i < 4; ++i)
            af[i] = *(f16x8*)(&As[(m0w + i * 16 + lm) * 40 + lg * 8]);
        #pragma unroll
        for (int j = 0; j < 4; ++j)
            bfr[j] = *(f16x8*)(&Bs[(n0w + j * 16 + lm) * 40 + lg * 8]);
        #pragma unroll
        for (int i = 0; i < 4; ++i)
            #pragma unroll
            for (int j = 0; j < 4; ++j)
                acc[i][j] = __builtin_amdgcn_mfma_f32_16x16x32_f16(
                    af[i], bfr[j], acc[i][j], 0, 0, 0);
        __syncthreads();
    }

    if constexpr (OMODE == 1) {
        // fp16 tile -> LDS, then head-major stores + fused scores
        __half (*Cs)[136] = (__half(*)[136])smem;
        #pragma unroll
        for (int i = 0; i < 4; ++i)
            #pragma unroll
            for (int r = 0; r < 4; ++r) {
                int lr = m0w + i * 16 + lg * 4 + r;
                #pragma unroll
                for (int j = 0; j < 4; ++j)
                    Cs[lr][n0w + j * 16 + lm] = __float2half(acc[i][j][r]);
            }
        __syncthreads();
        __half* hT = (__half*)Cp;   // [H][M][64]
        #pragma unroll
        for (int l = 0; l < 8; ++l) {
            int c = tid + l * 256;
            int rr = c >> 4, cc = c & 15;
            int gr = row0 + rr;
            if (gr < M) {
                int gcol = col0 + cc * 8;
                int head = gcol >> 6;
                *(uint4*)(hT + (size_t)head * M * 64 + (size_t)gr * 64 + (gcol & 63)) =
                    *(uint4*)(&Cs[rr][cc * 8]);
            }
        }
        // fused scores: thread t -> (row t>>1, head-sel t&1)
        {
            int row = tid >> 1, hsel = tid & 1;
            int gr = row0 + row;
            if (gr < M) {
                int ghead = (col0 >> 6) + hsel;
                const float* w1 = a1w + ghead * 64;
                const float* w2 = a2w + ghead * 64;
                const uint* cp = (const uint*)&Cs[row][hsel * 64];
                float s1 = 0.f, s2 = 0.f;
                #pragma unroll
                for (int j = 0; j < 32; ++j) {
                    uint u = cp[j];
                    float2 f = __half22float2(*(__half2*)&u);
                    s1 += f.x * w1[2*j] + f.y * w1[2*j+1];
                    s2 += f.x * w2[2*j] + f.y * w2[2*j+1];
                }
                a1v[(size_t)gr * H + ghead] = s1 + a1b[ghead];
                a2v[(size_t)gr * H + ghead] = s2 + a2b[ghead];
            }
        }
    } else {
        float* C = (float*)Cp;
        #pragma unroll
        for (int i = 0; i < 4; ++i)
            #pragma unroll
            for (int r = 0; r < 4; ++r) {
                int grow = row0 + m0w + i * 16 + lg * 4 + r;
                if (grow < M) {
                    #pragma unroll
                    for (int j = 0; j < 4; ++j) {
                        int gcol = col0 + n0w + j * 16 + lm;
                        float t = fmaxf(acc[i][j][r] + bias[gcol], 0.f);
                        C[(size_t)grow * CDIM + gcol] = t;
                    }
                }
            }
    }
}

// ---------------------------------------------------------------------------
// Edge aggregation v3: per-head passes (grid.y = head) over a head-major
// 12.8 MB table slice -> L2/L3-resident. Block = 4 waves = 4 nodes; one wave
// per (node, head); lane = dim. Output n-major fp16 [n][256].
// ---------------------------------------------------------------------------
__global__ __launch_bounds__(256) void agg_k(
    const __half* __restrict__ hT, const float* __restrict__ a1,
    const float* __restrict__ a2,
    const int* __restrict__ rowStart, const int* __restrict__ colI,
    const float* __restrict__ bias, __half* __restrict__ outN, int relu, int Nn)
{
    int hd = blockIdx.y;
    int n = blockIdx.x * 4 + (threadIdx.x >> 6);
    int lane = threadIdx.x & 63;
    if (n >= Nn) return;
    const __half* tab = hT + (size_t)hd * Nn * 64;
    float a1n = a1[(size_t)n * H + hd];
    int s = rowStart[n], e = rowStart[n + 1];
    float acc = 0.f, den = 0.f;
    for (int p = s; p < e; ++p) {
        int d = colI[p];
        float z = a1n + a2[(size_t)d * H + hd];
        z = (z > 0.f) ? z : ALPHA * z;
        float sv = __expf(z);
        den += sv;
        acc = fmaf(sv, __half2float(tab[(size_t)d * 64 + lane]), acc);
    }
    den = (den > 0.f) ? den : 1.f;
    float r = acc / den + bias[hd * 64 + lane];
    if (relu) r = fmaxf(r, 0.f);
    outN[(size_t)n * CDIM + hd * 64 + lane] = __float2half(r);
}

// ---------------------------------------------------------------------------
// Classifier: one wave per node; output dtype per flag (R2/R4/R5-proven).
// ---------------------------------------------------------------------------
__global__ __launch_bounds__(256) void cls_k(
    const float* __restrict__ feat, const float* __restrict__ Wcls,
    const float* __restrict__ bcls, void* __restrict__ out, int Nn,
    const int* __restrict__ flagp)
{
    int gtid = blockIdx.x * 256 + threadIdx.x;
    int n = gtid >> 6;
    int lane = threadIdx.x & 63;
    if (n >= Nn) return;
    const float* f = feat + (size_t)n * CDIM;
    float p0 = 0.f, p1 = 0.f, p2 = 0.f, p3 = 0.f;
    for (int k = lane; k < CDIM; k += 64) {
        float fv = f[k];
        p0 = fmaf(fv, Wcls[0 * CDIM + k], p0);
        p1 = fmaf(fv, Wcls[1 * CDIM + k], p1);
        p2 = fmaf(fv, Wcls[2 * CDIM + k], p2);
        p3 = fmaf(fv, Wcls[3 * CDIM + k], p3);
    }
    #pragma unroll
    for (int off = 32; off > 0; off >>= 1) {
        p0 += __shfl_xor(p0, off);
        p1 += __shfl_xor(p1, off);
        p2 += __shfl_xor(p2, off);
        p3 += __shfl_xor(p3, off);
    }
    if (lane < OUTC) {
        float pv = (lane == 0) ? p0 : (lane == 1) ? p1 : (lane == 2) ? p2 : p3;
        pv += bcls[lane];
        if (*flagp) ((__hip_bfloat16*)out)[(size_t)n * OUTC + lane] = __float2bfloat16(pv);
        else        ((float*)out)[(size_t)n * OUTC + lane] = pv;
    }
}

// ---------------------------------------------------------------------------
extern "C" void kernel_launch(void* const* d_in, const int* in_sizes, int n_in,
                              void* d_out, int out_size, void* d_ws, size_t ws_size,
                              hipStream_t stream)
{
    const void* x  = d_in[0];
    const int*  ei = (const int*)d_in[1];

    const int Nn = in_sizes[0] / CDIM;   // 100000
    const int Ee = in_sizes[1] / 2;      // 1600000
    const int* srcI = ei;
    const int* dstI = ei + Ee;

    char* wsp = (char*)d_ws;
    size_t off = 0;
    auto alloc = [&](size_t bytes) -> void* {
        void* p = wsp + off;
        off += (bytes + 255) & ~(size_t)255;
        return p;
    };
    __half* hT   = (__half*)alloc((size_t)Nn * CDIM * 2);  // 51.2 MB head-major table
    __half* hN   = (__half*)alloc((size_t)Nn * CDIM * 2);  // 51.2 MB n-major agg out
    float*  bufA = (float*)alloc((size_t)Nn * CDIM * 4);   // 102.4 MB fp32 collator out
    float*  a1v       = (float*)alloc((size_t)Nn * H * 4);
    float*  a2v       = (float*)alloc((size_t)Nn * H * 4);
    int*    rowStart  = (int*)alloc((size_t)(Nn + 1) * 4);
    int*    cursor    = (int*)alloc((size_t)Nn * 4);
    int*    colI      = (int*)alloc((size_t)Ee * 4);       // 6.4 MB
    int*    blockSums = (int*)alloc(512 * 4);
    int*    flag      = (int*)alloc(256);
    float*  wconv     = (float*)alloc((size_t)200000 * 4);
    __half* wh        = (__half*)alloc((size_t)200000 * 2);
    (void)ws_size; (void)n_in; (void)out_size;

    // dtype detect + weight conversion (proven machinery)
    detect_k<<<1, 256, 0, stream>>>((const uint32_t*)x, flag);
    WPtrs wp;
    int woff = 0;
    for (int i = 0; i < NW; ++i) {
        wp.p[i] = d_in[2 + i];
        wp.sz[i] = in_sizes[2 + i];
        wp.off[i] = woff;
        woff += in_sizes[2 + i];
    }
    {
        dim3 cgrid(256, NW);
        convert_k<<<cgrid, 256, 0, stream>>>(wp, wconv, wh, flag);
    }
    const float*  a11wf = wconv + wp.off[1];
    const float*  a11bf = wconv + wp.off[2];
    const float*  a12wf = wconv + wp.off[3];
    const float*  a12bf = wconv + wp.off[4];
    const float*  b1f   = wconv + wp.off[5];
    const float*  a21wf = wconv + wp.off[7];
    const float*  a21bf = wconv + wp.off[8];
    const float*  a22wf = wconv + wp.off[9];
    const float*  a22bf = wconv + wp.off[10];
    const float*  b2f   = wconv + wp.off[11];
    const float*  bcf   = wconv + wp.off[13];
    const float*  Wclsf = wconv + wp.off[14];
    const float*  bclsf = wconv + wp.off[15];
    const __half* W1h   = wh + wp.off[0];
    const __half* W2h   = wh + wp.off[6];
    const __half* Wch   = wh + wp.off[12];

    const int NB = (Nn + 255) / 256;   // 391 (fits scan2's 512)
    const int EB = (Ee + 255) / 256;

    // CSR build
    hipMemsetAsync(cursor, 0, (size_t)Nn * 4, stream);
    hist_k<<<EB, 256, 0, stream>>>(srcI, cursor, Ee);
    scan1_k<<<NB, 256, 0, stream>>>(cursor, blockSums, Nn);
    scan2_k<<<1, 512, 0, stream>>>(blockSums, NB);
    scan3_k<<<NB, 256, 0, stream>>>(cursor, blockSums, rowStart, cursor, Nn, Ee);
    scatter_k<<<EB, 256, 0, stream>>>(srcI, dstI, cursor, colI, Ee);

    dim3 ggrid((Nn + 127) / 128, CDIM / 128);   // (782, 2)
    dim3 agrid((Nn + 3) / 4, H);                // (25000, 4)

    // Layer 1: gemm(raw x) -> hT + scores; agg -> hN (relu)
    gemm_k<0, 1><<<ggrid, 256, 0, stream>>>(x, W1h, nullptr, hT, Nn, flag,
                                            a11wf, a11bf, a12wf, a12bf, a1v, a2v);
    agg_k<<<agrid, 256, 0, stream>>>(hT, a1v, a2v, rowStart, colI, b1f, hN, 1, Nn);

    // Layer 2: gemm(hN) -> hT + scores; agg -> hN (no relu; hN dead after gemm)
    gemm_k<1, 1><<<ggrid, 256, 0, stream>>>(hN, W2h, nullptr, hT, Nn, flag,
                                            a21wf, a21bf, a22wf, a22bf, a1v, a2v);
    agg_k<<<agrid, 256, 0, stream>>>(hT, a1v, a2v, rowStart, colI, b2f, hN, 0, Nn);

    // Collator (fp32 + bias + relu) + classifier
    gemm_k<1, 0><<<ggrid, 256, 0, stream>>>(hN, Wch, bcf, bufA, Nn, flag,
                                            nullptr, nullptr, nullptr, nullptr,
                                            nullptr, nullptr);
    cls_k<<<(Nn * 64 + 255) / 256, 256, 0, stream>>>(bufA, Wclsf, bclsf,
                                                     d_out, Nn, flag);
}

// Round 7
// 952.590 us; speedup vs baseline: 1.8182x; 1.8182x over previous
//
#include <hip/hip_runtime.h>
#include <hip/hip_bf16.h>
#include <hip/hip_fp16.h>
#include <stdint.h>

#define H 4
#define HID 64
#define CDIM 256   /* = H*HID = IN = FC */
#define OUTC 4
#define ALPHA 0.2f
#define NW 16      /* number of float weight inputs (d_in[2..17]) */

typedef __attribute__((ext_vector_type(8))) _Float16 f16x8;
typedef __attribute__((ext_vector_type(4))) float f32x4;

// ---------------------------------------------------------------------------
// dtype detection (R2/R4/R5-proven; real answer on this harness: fp32, flag=0)
// ---------------------------------------------------------------------------
__global__ void detect_k(const uint32_t* __restrict__ xw, int* __restrict__ flag) {
    __shared__ int sd[256];
    int t = threadIdx.x;
    int hits = 0;
    for (int i = 0; i < 16; ++i) {
        uint32_t w = xw[t * 16 + i];
        uint32_t ex = (w >> 7) & 0xffu;
        if (ex >= 100u && ex <= 145u) hits++;
    }
    sd[t] = hits;
    __syncthreads();
    for (int s = 128; s > 0; s >>= 1) {
        if (t < s) sd[t] += sd[t + s];
        __syncthreads();
    }
    if (t == 0) *flag = (sd[0] > 3000) ? 1 : 0;
}

// ---------------------------------------------------------------------------
// Convert all 16 weight tensors to fp32 AND fp16 in ws (branch on flag).
// ---------------------------------------------------------------------------
struct WPtrs {
    const void* p[NW];
    int sz[NW];
    int off[NW];
};

__global__ void convert_k(WPtrs ptrs, float* __restrict__ outf, __half* __restrict__ outh,
                          const int* __restrict__ flag) {
    int which = blockIdx.y;
    int n = ptrs.sz[which];
    int i = blockIdx.x * 256 + threadIdx.x;
    if (i >= n) return;
    float v;
    if (*flag) v = __bfloat162float(((const __hip_bfloat16*)ptrs.p[which])[i]);
    else       v = ((const float*)ptrs.p[which])[i];
    outf[ptrs.off[which] + i] = v;
    outh[ptrs.off[which] + i] = __float2half(v);
}

// ---------------------------------------------------------------------------
// CSR build: histogram -> scan -> scatter (stores dst and src per slot)
// ---------------------------------------------------------------------------
__global__ void hist_k(const int* __restrict__ srcI, int* __restrict__ counts, int Ee) {
    int e = blockIdx.x * 256 + threadIdx.x;
    if (e < Ee) atomicAdd(&counts[srcI[e]], 1);
}

__global__ void scan1_k(const int* __restrict__ counts, int* __restrict__ bs, int Nn) {
    __shared__ int sd[256];
    int t = threadIdx.x;
    int i = blockIdx.x * 256 + t;
    sd[t] = (i < Nn) ? counts[i] : 0;
    __syncthreads();
    for (int s = 128; s > 0; s >>= 1) {
        if (t < s) sd[t] += sd[t + s];
        __syncthreads();
    }
    if (t == 0) bs[blockIdx.x] = sd[0];
}

__global__ void scan2_k(int* __restrict__ bs, int nb) {
    __shared__ int sd[512];
    int t = threadIdx.x;
    int v = (t < nb) ? bs[t] : 0;
    sd[t] = v;
    __syncthreads();
    for (int offm = 1; offm < 512; offm <<= 1) {
        int add = (t >= offm) ? sd[t - offm] : 0;
        __syncthreads();
        sd[t] += add;
        __syncthreads();
    }
    if (t < nb) bs[t] = sd[t] - v;   // exclusive
}

__global__ void scan3_k(const int* __restrict__ counts, const int* __restrict__ bs,
                        int* __restrict__ rowStart, int* __restrict__ cur, int Nn, int Ee) {
    __shared__ int sd[256];
    int t = threadIdx.x;
    int i = blockIdx.x * 256 + t;
    int v = (i < Nn) ? counts[i] : 0;
    sd[t] = v;
    __syncthreads();
    for (int offm = 1; offm < 256; offm <<= 1) {
        int add = (t >= offm) ? sd[t - offm] : 0;
        __syncthreads();
        sd[t] += add;
        __syncthreads();
    }
    int excl = sd[t] - v + bs[blockIdx.x];
    if (i < Nn) { rowStart[i] = excl; cur[i] = excl; }
    if (i == Nn) rowStart[i] = Ee;
}

__global__ void scatter_k(const int* __restrict__ srcI, const int* __restrict__ dstI,
                          int* __restrict__ cur, int* __restrict__ colI,
                          int* __restrict__ colSrc, int Ee) {
    int e = blockIdx.x * 256 + threadIdx.x;
    if (e < Ee) {
        int s = srcI[e];
        int p = atomicAdd(&cur[s], 1);
        colI[p] = dstI[e];
        colSrc[p] = s;
    }
}

// ---------------------------------------------------------------------------
// f16 MFMA GEMM, 128x128 tile / 4 waves, BK=32, mfma_f32_16x16x32_f16.
// AMODE 0: A = raw x (fp32 or bf16 per *flag), convert to fp16 in staging.
// AMODE 1: A = fp16 n-major [M][256].
// OMODE 0: fp32 n-major out + bias + relu (collator).
// OMODE 1: fp16 n-major out [M][256] (pre-relu, no bias) + fused attention
//          scores a1v/a2v[n][head] (head's 64 dims sit inside this block's
//          128 cols -> no atomics, exact ownership).
// ---------------------------------------------------------------------------
template <int AMODE, int OMODE>
__global__ __launch_bounds__(256) void gemm_k(
    const void* __restrict__ Ap, const __half* __restrict__ B,
    const float* __restrict__ bias, void* __restrict__ Cp, int M,
    const int* __restrict__ flagp,
    const float* __restrict__ a1w, const float* __restrict__ a1b,
    const float* __restrict__ a2w, const float* __restrict__ a2b,
    float* __restrict__ a1v, float* __restrict__ a2v)
{
    __shared__ __align__(16) char smem[128 * 136 * 2];   // 34.8 KB
    short* As = (short*)smem;              // 128*40 shorts
    short* Bs = (short*)(smem + 10240);
    const int tid  = threadIdx.x;
    const int row0 = blockIdx.x * 128;
    const int col0 = blockIdx.y * 128;
    const int wave = tid >> 6, lane = tid & 63;
    const int m0w = (wave & 1) * 64;
    const int n0w = (wave >> 1) * 64;
    const int lm = lane & 15, lg = lane >> 4;
    const int isbf = (AMODE == 0) ? *flagp : 0;

    f32x4 acc[4][4] = {};

    for (int k0 = 0; k0 < CDIM; k0 += 32) {
        #pragma unroll
        for (int l = 0; l < 2; ++l) {
            int c = tid + l * 256;
            int m = c >> 2, kc = c & 3;
            int gr = row0 + m;
            uint4 q = make_uint4(0u, 0u, 0u, 0u);
            if constexpr (AMODE == 1) {
                const __half* A = (const __half*)Ap;
                if (gr < M) q = *(const uint4*)(A + (size_t)gr * CDIM + k0 + kc * 8);
            } else {
                if (gr < M) {
                    __half hv[8];
                    if (isbf) {
                        const uint4 qb = *(const uint4*)((const __hip_bfloat16*)Ap
                                           + (size_t)gr * CDIM + k0 + kc * 8);
                        const uint32_t* w = (const uint32_t*)&qb;
                        #pragma unroll
                        for (int p = 0; p < 4; ++p) {
                            hv[2*p]   = __float2half(__uint_as_float((w[p] & 0xffffu) << 16));
                            hv[2*p+1] = __float2half(__uint_as_float(w[p] & 0xffff0000u));
                        }
                    } else {
                        const float* A = (const float*)Ap + (size_t)gr * CDIM + k0 + kc * 8;
                        const float4 f0 = *(const float4*)A;
                        const float4 f1 = *(const float4*)(A + 4);
                        hv[0]=__float2half(f0.x); hv[1]=__float2half(f0.y);
                        hv[2]=__float2half(f0.z); hv[3]=__float2half(f0.w);
                        hv[4]=__float2half(f1.x); hv[5]=__float2half(f1.y);
                        hv[6]=__float2half(f1.z); hv[7]=__float2half(f1.w);
                    }
                    q = *(uint4*)hv;
                }
            }
            *(uint4*)(&As[m * 40 + kc * 8]) = q;
        }
        #pragma unroll
        for (int l = 0; l < 2; ++l) {
            int c = tid + l * 256;
            int nn = c >> 2, kc = c & 3;
            uint4 q = *(const uint4*)(B + (size_t)(col0 + nn) * CDIM + k0 + kc * 8);
            *(uint4*)(&Bs[nn * 40 + kc * 8]) = q;
        }
        __syncthreads();
        f16x8 af[4], bfr[4];
        #pragma unroll
        for (int i = 0; i < 4; ++i)
            af[i] = *(f16x8*)(&As[(m0w + i * 16 + lm) * 40 + lg * 8]);
        #pragma unroll
        for (int j = 0; j < 4; ++j)
            bfr[j] = *(f16x8*)(&Bs[(n0w + j * 16 + lm) * 40 + lg * 8]);
        #pragma unroll
        for (int i = 0; i < 4; ++i)
            #pragma unroll
            for (int j = 0; j < 4; ++j)
                acc[i][j] = __builtin_amdgcn_mfma_f32_16x16x32_f16(
                    af[i], bfr[j], acc[i][j], 0, 0, 0);
        __syncthreads();
    }

    if constexpr (OMODE == 1) {
        // fp16 tile -> LDS; n-major coalesced stores + fused scores
        __half (*Cs)[136] = (__half(*)[136])smem;
        #pragma unroll
        for (int i = 0; i < 4; ++i)
            #pragma unroll
            for (int r = 0; r < 4; ++r) {
                int lr = m0w + i * 16 + lg * 4 + r;
                #pragma unroll
                for (int j = 0; j < 4; ++j)
                    Cs[lr][n0w + j * 16 + lm] = __float2half(acc[i][j][r]);
            }
        __syncthreads();
        __half* C = (__half*)Cp;
        #pragma unroll
        for (int l = 0; l < 8; ++l) {
            int c = tid + l * 256;
            int rr = c >> 4, cc = c & 15;
            int gr = row0 + rr;
            if (gr < M)
                *(uint4*)(C + (size_t)gr * CDIM + col0 + cc * 8) = *(uint4*)(&Cs[rr][cc * 8]);
        }
        // fused scores: thread t -> (row t>>1, head-sel t&1); block covers 2 heads
        {
            int row = tid >> 1, hsel = tid & 1;
            int gr = row0 + row;
            if (gr < M) {
                int ghead = (col0 >> 6) + hsel;
                const float* w1 = a1w + ghead * 64;
                const float* w2 = a2w + ghead * 64;
                const uint* cp = (const uint*)&Cs[row][hsel * 64];
                float s1 = 0.f, s2 = 0.f;
                #pragma unroll
                for (int j = 0; j < 32; ++j) {
                    uint u = cp[j];
                    float2 f = __half22float2(*(__half2*)&u);
                    s1 += f.x * w1[2*j] + f.y * w1[2*j+1];
                    s2 += f.x * w2[2*j] + f.y * w2[2*j+1];
                }
                a1v[(size_t)gr * H + ghead] = s1 + a1b[ghead];
                a2v[(size_t)gr * H + ghead] = s2 + a2b[ghead];
            }
        }
    } else {
        float* C = (float*)Cp;
        #pragma unroll
        for (int i = 0; i < 4; ++i)
            #pragma unroll
            for (int r = 0; r < 4; ++r) {
                int grow = row0 + m0w + i * 16 + lg * 4 + r;
                if (grow < M) {
                    #pragma unroll
                    for (int j = 0; j < 4; ++j) {
                        int gcol = col0 + n0w + j * 16 + lm;
                        float t = fmaxf(acc[i][j][r] + bias[gcol], 0.f);
                        C[(size_t)grow * CDIM + gcol] = t;
                    }
                }
            }
    }
}

// ---------------------------------------------------------------------------
// Edge scores: thread t -> (slot p = t>>2, head = t&3).
// Removes the colI->a2->exp dependent chain (and 16x-redundant exp) from agg.
// ---------------------------------------------------------------------------
__global__ void escore_k(const int* __restrict__ colSrc, const int* __restrict__ colI,
                         const float* __restrict__ a1, const float* __restrict__ a2,
                         float* __restrict__ sExp, int Ee)
{
    int t = blockIdx.x * 256 + threadIdx.x;
    if (t >= Ee * 4) return;
    int p = t >> 2, head = t & 3;
    float z = a1[(size_t)colSrc[p] * H + head] + a2[(size_t)colI[p] * H + head];
    z = (z > 0.f) ? z : ALPHA * z;
    sExp[t] = __expf(z);
}

// ---------------------------------------------------------------------------
// Edge aggregation (R5-proven structure): block = 4 waves per node; wave w
// takes slots s+w, s+w+4,...; lane covers dims lane*4..lane*4+3 (head =
// lane>>4) via one ushort4 -> full 512B row per wave-instr. sExp replaces the
// score chain; next-edge colI/sExp software-prefetched. LDS cross-wave reduce.
// ---------------------------------------------------------------------------
__global__ __launch_bounds__(256) void agg_k(
    const __half* __restrict__ h, const float* __restrict__ sExp,
    const int* __restrict__ rowStart, const int* __restrict__ colI,
    const float* __restrict__ bias, __half* __restrict__ outp, int relu)
{
    __shared__ float accL[4][64][4];
    __shared__ float denL[4][64];
    int n = blockIdx.x;
    int tid = threadIdx.x;
    int wave = tid >> 6, lane = tid & 63;
    int head = lane >> 4;
    int s = rowStart[n], e = rowStart[n + 1];
    float ac0 = 0.f, ac1 = 0.f, ac2 = 0.f, ac3 = 0.f, den = 0.f;
    int p = s + wave;
    int d = 0; float sv = 0.f;
    if (p < e) { d = colI[p]; sv = sExp[(size_t)p * H + head]; }
    while (p < e) {
        int pn = p + 4;
        int dn = 0; float svn = 0.f;
        if (pn < e) { dn = colI[pn]; svn = sExp[(size_t)pn * H + head]; }
        ushort4 u = *(const ushort4*)(h + (size_t)d * CDIM + lane * 4);
        den += sv;
        ac0 = fmaf(sv, __half2float(__ushort_as_half(u.x)), ac0);
        ac1 = fmaf(sv, __half2float(__ushort_as_half(u.y)), ac1);
        ac2 = fmaf(sv, __half2float(__ushort_as_half(u.z)), ac2);
        ac3 = fmaf(sv, __half2float(__ushort_as_half(u.w)), ac3);
        p = pn; d = dn; sv = svn;
    }
    accL[wave][lane][0] = ac0;
    accL[wave][lane][1] = ac1;
    accL[wave][lane][2] = ac2;
    accL[wave][lane][3] = ac3;
    denL[wave][lane] = den;
    __syncthreads();
    int l = tid >> 2, j = tid & 3;
    float a = accL[0][l][j] + accL[1][l][j] + accL[2][l][j] + accL[3][l][j];
    float dn2 = denL[0][l] + denL[1][l] + denL[2][l] + denL[3][l];
    dn2 = (dn2 > 0.f) ? dn2 : 1.f;
    float r = a / dn2 + bias[tid];
    if (relu) r = fmaxf(r, 0.f);
    outp[(size_t)n * CDIM + tid] = __float2half(r);
}

// ---------------------------------------------------------------------------
// Classifier: one wave per node; output dtype per flag (proven).
// ---------------------------------------------------------------------------
__global__ __launch_bounds__(256) void cls_k(
    const float* __restrict__ feat, const float* __restrict__ Wcls,
    const float* __restrict__ bcls, void* __restrict__ out, int Nn,
    const int* __restrict__ flagp)
{
    int gtid = blockIdx.x * 256 + threadIdx.x;
    int n = gtid >> 6;
    int lane = threadIdx.x & 63;
    if (n >= Nn) return;
    const float* f = feat + (size_t)n * CDIM;
    float p0 = 0.f, p1 = 0.f, p2 = 0.f, p3 = 0.f;
    for (int k = lane; k < CDIM; k += 64) {
        float fv = f[k];
        p0 = fmaf(fv, Wcls[0 * CDIM + k], p0);
        p1 = fmaf(fv, Wcls[1 * CDIM + k], p1);
        p2 = fmaf(fv, Wcls[2 * CDIM + k], p2);
        p3 = fmaf(fv, Wcls[3 * CDIM + k], p3);
    }
    #pragma unroll
    for (int off = 32; off > 0; off >>= 1) {
        p0 += __shfl_xor(p0, off);
        p1 += __shfl_xor(p1, off);
        p2 += __shfl_xor(p2, off);
        p3 += __shfl_xor(p3, off);
    }
    if (lane < OUTC) {
        float pv = (lane == 0) ? p0 : (lane == 1) ? p1 : (lane == 2) ? p2 : p3;
        pv += bcls[lane];
        if (*flagp) ((__hip_bfloat16*)out)[(size_t)n * OUTC + lane] = __float2bfloat16(pv);
        else        ((float*)out)[(size_t)n * OUTC + lane] = pv;
    }
}

// ---------------------------------------------------------------------------
extern "C" void kernel_launch(void* const* d_in, const int* in_sizes, int n_in,
                              void* d_out, int out_size, void* d_ws, size_t ws_size,
                              hipStream_t stream)
{
    const void* x  = d_in[0];
    const int*  ei = (const int*)d_in[1];

    const int Nn = in_sizes[0] / CDIM;   // 100000
    const int Ee = in_sizes[1] / 2;      // 1600000
    const int* srcI = ei;
    const int* dstI = ei + Ee;

    char* wsp = (char*)d_ws;
    size_t off = 0;
    auto alloc = [&](size_t bytes) -> void* {
        void* p = wsp + off;
        off += (bytes + 255) & ~(size_t)255;
        return p;
    };
    __half* hA   = (__half*)alloc((size_t)Nn * CDIM * 2);  // 51.2 MB
    __half* hB   = (__half*)alloc((size_t)Nn * CDIM * 2);  // 51.2 MB
    float*  bufA = (float*)alloc((size_t)Nn * CDIM * 4);   // 102.4 MB fp32 collator out
    float*  a1v       = (float*)alloc((size_t)Nn * H * 4);
    float*  a2v       = (float*)alloc((size_t)Nn * H * 4);
    float*  sExp      = (float*)alloc((size_t)Ee * H * 4); // 25.6 MB
    int*    rowStart  = (int*)alloc((size_t)(Nn + 1) * 4);
    int*    cursor    = (int*)alloc((size_t)Nn * 4);
    int*    colI      = (int*)alloc((size_t)Ee * 4);       // 6.4 MB
    int*    colSrc    = (int*)alloc((size_t)Ee * 4);       // 6.4 MB
    int*    blockSums = (int*)alloc(512 * 4);
    int*    flag      = (int*)alloc(256);
    float*  wconv     = (float*)alloc((size_t)200000 * 4);
    __half* wh        = (__half*)alloc((size_t)200000 * 2);
    (void)ws_size; (void)n_in; (void)out_size;

    // dtype detect + weight conversion (proven machinery)
    detect_k<<<1, 256, 0, stream>>>((const uint32_t*)x, flag);
    WPtrs wp;
    int woff = 0;
    for (int i = 0; i < NW; ++i) {
        wp.p[i] = d_in[2 + i];
        wp.sz[i] = in_sizes[2 + i];
        wp.off[i] = woff;
        woff += in_sizes[2 + i];
    }
    {
        dim3 cgrid(256, NW);
        convert_k<<<cgrid, 256, 0, stream>>>(wp, wconv, wh, flag);
    }
    const float*  a11wf = wconv + wp.off[1];
    const float*  a11bf = wconv + wp.off[2];
    const float*  a12wf = wconv + wp.off[3];
    const float*  a12bf = wconv + wp.off[4];
    const float*  b1f   = wconv + wp.off[5];
    const float*  a21wf = wconv + wp.off[7];
    const float*  a21bf = wconv + wp.off[8];
    const float*  a22wf = wconv + wp.off[9];
    const float*  a22bf = wconv + wp.off[10];
    const float*  b2f   = wconv + wp.off[11];
    const float*  bcf   = wconv + wp.off[13];
    const float*  Wclsf = wconv + wp.off[14];
    const float*  bclsf = wconv + wp.off[15];
    const __half* W1h   = wh + wp.off[0];
    const __half* W2h   = wh + wp.off[6];
    const __half* Wch   = wh + wp.off[12];

    const int NB = (Nn + 255) / 256;   // 391 (fits scan2's 512)
    const int EB = (Ee + 255) / 256;
    const int SB = (Ee * 4 + 255) / 256;

    // CSR build
    hipMemsetAsync(cursor, 0, (size_t)Nn * 4, stream);
    hist_k<<<EB, 256, 0, stream>>>(srcI, cursor, Ee);
    scan1_k<<<NB, 256, 0, stream>>>(cursor, blockSums, Nn);
    scan2_k<<<1, 512, 0, stream>>>(blockSums, NB);
    scan3_k<<<NB, 256, 0, stream>>>(cursor, blockSums, rowStart, cursor, Nn, Ee);
    scatter_k<<<EB, 256, 0, stream>>>(srcI, dstI, cursor, colI, colSrc, Ee);

    dim3 ggrid((Nn + 127) / 128, CDIM / 128);   // (782, 2)

    // Layer 1: gemm(raw x) -> hA (+ fused scores); escore; agg -> hB (relu)
    gemm_k<0, 1><<<ggrid, 256, 0, stream>>>(x, W1h, nullptr, hA, Nn, flag,
                                            a11wf, a11bf, a12wf, a12bf, a1v, a2v);
    escore_k<<<SB, 256, 0, stream>>>(colSrc, colI, a1v, a2v, sExp, Ee);
    agg_k<<<Nn, 256, 0, stream>>>(hA, sExp, rowStart, colI, b1f, hB, 1);

    // Layer 2: gemm(hB) -> hA (+ fused scores); escore; agg -> hB
    gemm_k<1, 1><<<ggrid, 256, 0, stream>>>(hB, W2h, nullptr, hA, Nn, flag,
                                            a21wf, a21bf, a22wf, a22bf, a1v, a2v);
    escore_k<<<SB, 256, 0, stream>>>(colSrc, colI, a1v, a2v, sExp, Ee);
    agg_k<<<Nn, 256, 0, stream>>>(hA, sExp, rowStart, colI, b2f, hB, 0);

    // Collator (fp32 + bias + relu) + classifier
    gemm_k<1, 0><<<ggrid, 256, 0, stream>>>(hB, Wch, bcf, bufA, Nn, flag,
                                            nullptr, nullptr, nullptr, nullptr,
                                            nullptr, nullptr);
    cls_k<<<(Nn * 64 + 255) / 256, 256, 0, stream>>>(bufA, Wclsf, bclsf,
                                                     d_out, Nn, flag);
}